// Round 10
// baseline (893.371 us; speedup 1.0000x reference)
//
#include <hip/hip_runtime.h>
#include <hip/hip_fp16.h>

#define N_NODES 50000
#define NROW    50176                    // padded rows per graph (multiple of 1024)
#define N_EDGES 800000
#define BATCH   4
#define DIM     64
#define NEG_SLOPE 0.2f
#define K_CHUNK 16
#define CHUNK_E (N_EDGES / K_CHUNK)      // 50000 exactly
#define NTOT2   (BATCH * NROW)           // 200704 = 196*1024 exactly
#define SCAN_BLOCKS (NTOT2 / 1024)       // 196
#define HALF_ROWS 25088                  // NROW/2
#define HALF_WORDS 12544                 // HALF_ROWS/2 packed u16 words
#define CLS_PER_G 32
#define CLS_ROWS  (NROW / CLS_PER_G)     // 1568 rows per placement class

// ---------------------------------------------------------------------------
// Index dtype detector (int64 vs int32): if int64 little-endian with values
// < 2^31, every odd 32-bit word is 0. flag=1 for int64, 0 for int32.
// ---------------------------------------------------------------------------
__global__ void detect_idx_kernel(const unsigned* __restrict__ ei, int* flag) {
    __shared__ int any;
    if (threadIdx.x == 0) any = 0;
    __syncthreads();
    unsigned v = ei[threadIdx.x * 2 + 1];
    if (v != 0) atomicOr(&any, 1);
    __syncthreads();
    if (threadIdx.x == 0) *flag = (any ? 0 : 1);
}

__device__ __forceinline__ int load_idx(const void* p, long long i, int is64) {
    if (is64) return (int)(((const long long*)p)[i]);
    return ((const int*)p)[i];
}

// ---------------------------------------------------------------------------
// Histogram stage 1: private LDS histogram per (graph, chunk, row-half).
// u16 counters packed in u32. Coalesced dump, no global atomics.
// ---------------------------------------------------------------------------
__global__ __launch_bounds__(256)
void hist_partial_kernel(const void* __restrict__ ei, const int* __restrict__ flag,
                         unsigned* __restrict__ P32) {
    __shared__ unsigned lds[HALF_WORDS];          // 50 KB
    int t = threadIdx.x;
    int b = blockIdx.x >> 5;
    int k = (blockIdx.x >> 1) & (K_CHUNK - 1);
    int h = blockIdx.x & 1;
    for (int i = t; i < HALF_WORDS; i += 256) lds[i] = 0;
    __syncthreads();
    const int is64 = *flag;
    const int rowLo = h * HALF_ROWS;
    const long long base = (long long)b * 2LL * N_EDGES + (long long)k * CHUNK_E;
    for (int i = t; i < CHUNK_E; i += 256) {
        int row = load_idx(ei, base + i, is64);
        unsigned r = (unsigned)(row - rowLo);
        if (r < HALF_ROWS)
            atomicAdd(&lds[r >> 1], 1u << ((r & 1) * 16));
    }
    __syncthreads();
    unsigned* dst = P32 + (long long)(b * K_CHUNK + k) * (NROW / 2) + h * HALF_WORDS;
    for (int i = t; i < HALF_WORDS; i += 256) dst[i] = lds[i];
}

// ---------------------------------------------------------------------------
// Stage 2: deg4[b][row] = sum_k counts (prefix no longer needed: placement
// is class-owned now).
// ---------------------------------------------------------------------------
__global__ __launch_bounds__(256)
void merge_deg_kernel(const unsigned short* __restrict__ P16, int* __restrict__ deg4) {
    int gid = blockIdx.x * 256 + threadIdx.x;
    if (gid >= NTOT2) return;
    int b = gid / NROW;
    int row = gid - b * NROW;
    const unsigned short* p = P16 + (long long)(b * K_CHUNK) * NROW + row;
    int s = 0;
#pragma unroll
    for (int k = 0; k < K_CHUNK; ++k) s += p[(long long)k * NROW];
    deg4[gid] = s;
}

// ---------------------------------------------------------------------------
// Hierarchical exclusive scan over deg4[NTOT2] -> rowptr4.
// ---------------------------------------------------------------------------
__global__ __launch_bounds__(256)
void scan_partial_kernel(const int* __restrict__ deg, int* __restrict__ bsum) {
    __shared__ int sdata[256];
    int t = threadIdx.x;
    int base = blockIdx.x * 1024;
    int s = 0;
#pragma unroll
    for (int i = 0; i < 4; ++i) s += deg[base + i * 256 + t];
    sdata[t] = s;
    __syncthreads();
    for (int off = 128; off > 0; off >>= 1) {
        if (t < off) sdata[t] += sdata[t + off];
        __syncthreads();
    }
    if (t == 0) bsum[blockIdx.x] = sdata[0];
}

__global__ __launch_bounds__(256)
void scan_bsum_kernel(int* __restrict__ bsum, int* __restrict__ rowptr) {
    __shared__ int sdata[256];
    int t = threadIdx.x;
    int v = (t < SCAN_BLOCKS) ? bsum[t] : 0;
    sdata[t] = v;
    __syncthreads();
    for (int off = 1; off < 256; off <<= 1) {
        int x = (t >= off) ? sdata[t - off] : 0;
        __syncthreads();
        sdata[t] += x;
        __syncthreads();
    }
    if (t < SCAN_BLOCKS) bsum[t] = sdata[t] - v;
    if (t == 255) rowptr[NTOT2] = sdata[255];
}

__global__ __launch_bounds__(256)
void scan_apply_kernel(const int* __restrict__ deg, const int* __restrict__ bsum,
                       int* __restrict__ rowptr) {
    __shared__ int sdata[256];
    int t = threadIdx.x;
    int base = blockIdx.x * 1024 + t * 4;
    int4 q = *(const int4*)(deg + base);          // NTOT2 exact multiple of 1024
    int s = q.x + q.y + q.z + q.w;
    sdata[t] = s;
    __syncthreads();
    for (int off = 1; off < 256; off <<= 1) {
        int x = (t >= off) ? sdata[t - off] : 0;
        __syncthreads();
        sdata[t] += x;
        __syncthreads();
    }
    int run = bsum[blockIdx.x] + sdata[t] - s;
    rowptr[base + 0] = run; run += q.x;
    rowptr[base + 1] = run; run += q.y;
    rowptr[base + 2] = run; run += q.z;
    rowptr[base + 3] = run;
}

// ---------------------------------------------------------------------------
// CLASS-OWNED placement: each block owns CLS_ROWS rows of one graph and is
// the ONLY writer of its contiguous colw slice -> colw sectors fill
// completely in one L2 (kills the 4x write amplification seen in R5-R8).
// Block scans the graph's full row array (coalesced), filters its range,
// places via LDS u32 cursors initialized from rowptr. Same-graph blocks are
// pinned to an XCD pair via blockIdx&7 so redundant row reads L2-share.
// ---------------------------------------------------------------------------
__global__ __launch_bounds__(1024)
void placement_kernel(const void* __restrict__ ei, const float* __restrict__ ew,
                      const int* __restrict__ flag,
                      const int* __restrict__ rowptr4,
                      int2* __restrict__ colw, int nGraphs, int bStart, int sub) {
    __shared__ unsigned cur[CLS_ROWS];            // 6.3 KB
    const int is64 = *flag;
    int b, cls;
    if (nGraphs == BATCH) {                       // big path: 128 blocks
        int xcd = blockIdx.x & 7;
        b = xcd >> 1;                             // graph on XCD pair {2b,2b+1}
        cls = (blockIdx.x >> 3) * 2 + (xcd & 1);  // 0..31
    } else {                                      // small path: 32 blocks
        b = bStart;
        cls = blockIdx.x;
    }
    const int lo = cls * CLS_ROWS;
    const int* rp = rowptr4 + b * NROW;
    for (int r = threadIdx.x; r < CLS_ROWS; r += 1024) cur[r] = (unsigned)rp[lo + r];
    __syncthreads();
    const long long ebase = (long long)b * 2LL * N_EDGES;
    const float* ewb = ew + (long long)b * N_EDGES;
    for (int i = threadIdx.x; i < N_EDGES; i += 1024) {
        int row = load_idx(ei, ebase + i, is64);
        unsigned r = (unsigned)(row - lo);
        if (r < CLS_ROWS) {
            int col = load_idx(ei, ebase + N_EDGES + i, is64);
            float w = ewb[i];
            int pos = (int)atomicAdd(&cur[r], 1u) - sub;
            colw[pos] = make_int2(col, __float_as_int(w));
        }
    }
}

// ---------------------------------------------------------------------------
// S = act(X) @ W  -> fp16 [N][64]. W in LDS; thread = (row, col-quad).
// ---------------------------------------------------------------------------
template <bool LEAKY>
__global__ __launch_bounds__(256)
void gemm_kernel(const float* __restrict__ X, const float* __restrict__ W,
                 __half* __restrict__ S) {
    __shared__ float Wl[64 * 64];
    int t = threadIdx.x;
    for (int i = t; i < 64 * 64; i += 256) Wl[i] = W[i];
    __syncthreads();

    int dq = t & 15;
    int rl = t >> 4;
    int rowBase = blockIdx.x * 64;
    for (int r = rl; r < 64; r += 16) {
        int row = rowBase + r;
        if (row >= N_NODES) break;
        const float* xr = X + (long long)row * DIM;
        float4 acc = {0.f, 0.f, 0.f, 0.f};
#pragma unroll
        for (int k = 0; k < 64; k += 4) {
            float4 xv = *(const float4*)(xr + k);
            if (LEAKY) {
                xv.x = xv.x > 0.f ? xv.x : NEG_SLOPE * xv.x;
                xv.y = xv.y > 0.f ? xv.y : NEG_SLOPE * xv.y;
                xv.z = xv.z > 0.f ? xv.z : NEG_SLOPE * xv.z;
                xv.w = xv.w > 0.f ? xv.w : NEG_SLOPE * xv.w;
            }
#pragma unroll
            for (int kk = 0; kk < 4; ++kk) {
                float xs = kk == 0 ? xv.x : kk == 1 ? xv.y : kk == 2 ? xv.z : xv.w;
                float4 wv = *(const float4*)(&Wl[(k + kk) * 64 + dq * 4]);
                acc.x += xs * wv.x;
                acc.y += xs * wv.y;
                acc.z += xs * wv.z;
                acc.w += xs * wv.w;
            }
        }
        __half2* o = (__half2*)(S + (long long)row * DIM + dq * 4);
        o[0] = __floats2half2_rn(acc.x, acc.y);
        o[1] = __floats2half2_rn(acc.z, acc.w);
    }
}

// ---------------------------------------------------------------------------
// Pull aggregation (R7 form, proven): wave per node, two edge slots x 32
// lanes, __half2 gathers; shfl_xor(32) combine; coalesced float2 store.
// ---------------------------------------------------------------------------
__global__ __launch_bounds__(256)
void aggregate_kernel(const int* __restrict__ rowptr4, const int2* __restrict__ colw,
                      const __half* __restrict__ src, const float* __restrict__ bias,
                      float* __restrict__ dstBase, int bStart, int colwLocal) {
    const int BLKS = NROW / 4;                     // 12544
    int bi = blockIdx.x / BLKS;
    int node = (blockIdx.x % BLKS) * 4 + (threadIdx.x >> 6);
    int tl = threadIdx.x & 63;
    int lane = tl & 31;                            // dim pair id (dims 2l, 2l+1)
    int slot = tl >> 5;                            // 0: even edges, 1: odd edges
    int b = bStart + bi;
    if (node >= N_NODES) return;
    const int* rp = rowptr4 + b * NROW;
    int sub = colwLocal ? b * N_EDGES : 0;
    int s = rp[node] - sub;
    int e = rp[node + 1] - sub;
    float2 acc = {0.f, 0.f};
    int k = s + slot;
    for (; k + 14 < e; k += 16) {                  // 8 pair-steps = 16 edges/wave
        int2 c[8];
        float2 v[8];
#pragma unroll
        for (int j = 0; j < 8; ++j) c[j] = colw[k + 2 * j];
#pragma unroll
        for (int j = 0; j < 8; ++j) {
            __half2 h = *(const __half2*)(src + (long long)c[j].x * DIM + 2 * lane);
            v[j] = __half22float2(h);
        }
#pragma unroll
        for (int j = 0; j < 8; ++j) {
            float w = __int_as_float(c[j].y);
            acc.x += w * v[j].x;
            acc.y += w * v[j].y;
        }
    }
    for (; k < e; k += 2) {
        int2 c = colw[k];
        __half2 h = *(const __half2*)(src + (long long)c.x * DIM + 2 * lane);
        float2 v = __half22float2(h);
        float w = __int_as_float(c.y);
        acc.x += w * v.x;
        acc.y += w * v.y;
    }
    acc.x += __shfl_xor(acc.x, 32, 64);
    acc.y += __shfl_xor(acc.y, 32, 64);
    if (slot == 0) {
        float2 bb = *(const float2*)(bias + 2 * lane);
        float2 o;
        o.x = acc.x + bb.x;
        o.y = acc.y + bb.y;
        *(float2*)(dstBase + (long long)b * N_NODES * DIM +
                   (long long)node * DIM + 2 * lane) = o;
    }
}

extern "C" void kernel_launch(void* const* d_in, const int* in_sizes, int n_in,
                              void* d_out, int out_size, void* d_ws, size_t ws_size,
                              hipStream_t stream) {
    const float* bx = (const float*)d_in[0];
    const void*  ei = d_in[1];
    const float* ew = (const float*)d_in[2];
    const float* W0 = (const float*)d_in[3];
    const float* b0 = (const float*)d_in[4];
    const float* W1 = (const float*)d_in[5];
    const float* b1 = (const float*)d_in[6];
    float* out = (float*)d_out;

    // ---- workspace layout (big path = 40.03 MB, proven R5-R8) ----
    char* ws = (char*)d_ws;
    int*      flag     = (int*)ws;                       // [0,256)
    int*      bsum     = (int*)(ws + 256);               // [256,1280)
    int*      deg4     = (int*)(ws + 1280);              // [1280,804096)
    int*      rowptr4  = (int*)(ws + 804096);            // [804096,1607168)
    unsigned* P32      = (unsigned*)(ws + 1607168);      // [1607168,8029696) 6.42MB
    unsigned short* P16 = (unsigned short*)P32;
    __half*   support0 = (__half*)(ws + 8029696);        // 6.4 MB
    int2*     colw     = (int2*)(ws + 14429696);         // big: 25.6 MB
    const size_t NEED_BIG = 14429696ull + (size_t)BATCH * N_EDGES * 8ull; // 40.03MB
    const bool big = ws_size >= NEED_BIG;
    __half* support1 = big ? (__half*)P32                // P16 dead after merge
                           : (__half*)(ws + 14429696 + (size_t)N_EDGES * 8);
    const long long ND = (long long)N_NODES * DIM;

    detect_idx_kernel<<<1, 64, 0, stream>>>((const unsigned*)ei, flag);

    // ---- batched atomic-free CSR skeleton ----
    hist_partial_kernel<<<BATCH * K_CHUNK * 2, 256, 0, stream>>>(ei, flag, P32);
    merge_deg_kernel<<<(NTOT2 + 255) / 256, 256, 0, stream>>>(P16, deg4);
    scan_partial_kernel<<<SCAN_BLOCKS, 256, 0, stream>>>(deg4, bsum);
    scan_bsum_kernel<<<1, 256, 0, stream>>>(bsum, rowptr4);
    scan_apply_kernel<<<SCAN_BLOCKS, 256, 0, stream>>>(deg4, bsum, rowptr4);

    // ---- layer-1 support (graph-independent, fp16) ----
    gemm_kernel<false><<<(N_NODES + 63) / 64, 256, 0, stream>>>(bx, W0, support0);

    const int AGG_BLKS = NROW / 4;                 // 12544 per graph

    if (big) {
        placement_kernel<<<BATCH * CLS_PER_G, 1024, 0, stream>>>(
            ei, ew, flag, rowptr4, colw, BATCH, 0, 0);
        aggregate_kernel<<<BATCH * AGG_BLKS, 256, 0, stream>>>(
            rowptr4, colw, support0, b0, out, 0, 0);
        for (int b = 0; b < BATCH; ++b) {
            gemm_kernel<true><<<(N_NODES + 63) / 64, 256, 0, stream>>>(
                out + (long long)b * ND, W1, support1);
            aggregate_kernel<<<AGG_BLKS, 256, 0, stream>>>(
                rowptr4, colw, support1, b1, out, b, 0);
        }
    } else {
        for (int b = 0; b < BATCH; ++b) {
            placement_kernel<<<CLS_PER_G, 1024, 0, stream>>>(
                ei, ew, flag, rowptr4, colw, 1, b, b * N_EDGES);
            aggregate_kernel<<<AGG_BLKS, 256, 0, stream>>>(
                rowptr4, colw, support0, b0, out, b, 1);
            gemm_kernel<true><<<(N_NODES + 63) / 64, 256, 0, stream>>>(
                out + (long long)b * ND, W1, support1);
            aggregate_kernel<<<AGG_BLKS, 256, 0, stream>>>(
                rowptr4, colw, support1, b1, out, b, 1);
        }
    }
}

// Round 11
// 605.829 us; speedup vs baseline: 1.4746x; 1.4746x over previous
//
#include <hip/hip_runtime.h>
#include <hip/hip_fp16.h>

#define N_NODES 50000
#define NROW    50176                    // padded rows per graph (multiple of 1024)
#define N_EDGES 800000
#define BATCH   4
#define DIM     64
#define NEG_SLOPE 0.2f
#define K_CHUNK 16
#define CHUNK_E (N_EDGES / K_CHUNK)      // 50000 (< 65536: u16 counts guaranteed)
#define CSPLIT  25000                    // col half threshold
#define NB      (2 * NROW)               // bins per graph (row, colhalf) = 100352
#define QBINS   (NB / 4)                 // 25088 bins per quarter-block
#define QWORDS  (QBINS / 2)              // 12544 packed-u16 words = 50 KB LDS
#define NTOT2H  (BATCH * NB)             // 401408 = 392*1024 exactly
#define SCAN_BLOCKS2 (NTOT2H / 1024)     // 392
#define AGG_BLKS (NROW / 4)              // 12544

// ---------------------------------------------------------------------------
// Index dtype detector (int64 vs int32).
// ---------------------------------------------------------------------------
__global__ void detect_idx_kernel(const unsigned* __restrict__ ei, int* flag) {
    __shared__ int any;
    if (threadIdx.x == 0) any = 0;
    __syncthreads();
    unsigned v = ei[threadIdx.x * 2 + 1];
    if (v != 0) atomicOr(&any, 1);
    __syncthreads();
    if (threadIdx.x == 0) *flag = (any ? 0 : 1);
}

__device__ __forceinline__ int load_idx(const void* p, long long i, int is64) {
    if (is64) return (int)(((const long long*)p)[i]);
    return ((const int*)p)[i];
}

// ---------------------------------------------------------------------------
// Histogram over (row, colhalf) bins: one block per (graph, chunk, quarter).
// u16 counters packed in u32, 50 KB LDS. Coalesced dump, no global atomics.
// ---------------------------------------------------------------------------
__global__ __launch_bounds__(256)
void hist_partial_kernel(const void* __restrict__ ei, const int* __restrict__ flag,
                         unsigned* __restrict__ P32) {
    __shared__ unsigned lds[QWORDS];
    int t = threadIdx.x;
    int b = blockIdx.x >> 6;
    int k = (blockIdx.x >> 2) & (K_CHUNK - 1);
    int q = blockIdx.x & 3;
    for (int i = t; i < QWORDS; i += 256) lds[i] = 0;
    __syncthreads();
    const int is64 = *flag;
    const int binLo = q * QBINS;
    const long long ebase = (long long)b * 2LL * N_EDGES + (long long)k * CHUNK_E;
    for (int i = t; i < CHUNK_E; i += 256) {
        int row = load_idx(ei, ebase + i, is64);
        int col = load_idx(ei, ebase + N_EDGES + i, is64);
        int bin = (row << 1) | (col >= CSPLIT);
        unsigned r = (unsigned)(bin - binLo);
        if (r < QBINS)
            atomicAdd(&lds[r >> 1], 1u << ((r & 1) * 16));
    }
    __syncthreads();
    unsigned* dst = P32 + ((long long)(b * K_CHUNK + k) * NB >> 1) + q * QWORDS;
    for (int i = t; i < QWORDS; i += 256) dst[i] = lds[i];
}

// ---------------------------------------------------------------------------
// Per bin: deg = sum over chunks; P16 becomes exclusive chunk-prefix in place.
// ---------------------------------------------------------------------------
__global__ __launch_bounds__(256)
void merge_prefix_kernel(unsigned short* __restrict__ P16, int* __restrict__ deg) {
    int gid = blockIdx.x * 256 + threadIdx.x;
    if (gid >= NTOT2H) return;
    int b = gid / NB;
    int bin = gid - b * NB;
    unsigned short* p = P16 + (long long)(b * K_CHUNK) * NB + bin;
    int run = 0;
#pragma unroll
    for (int k = 0; k < K_CHUNK; ++k) {
        int c = p[(long long)k * NB];
        p[(long long)k * NB] = (unsigned short)run;
        run += c;
    }
    deg[gid] = run;
}

// ---------------------------------------------------------------------------
// Hierarchical exclusive scan over deg[NTOT2H] -> rowptrH (in place).
// ---------------------------------------------------------------------------
__global__ __launch_bounds__(256)
void scan_partial_kernel(const int* __restrict__ deg, int* __restrict__ bsum) {
    __shared__ int sdata[256];
    int t = threadIdx.x;
    int base = blockIdx.x * 1024;
    int s = 0;
#pragma unroll
    for (int i = 0; i < 4; ++i) s += deg[base + i * 256 + t];
    sdata[t] = s;
    __syncthreads();
    for (int off = 128; off > 0; off >>= 1) {
        if (t < off) sdata[t] += sdata[t + off];
        __syncthreads();
    }
    if (t == 0) bsum[blockIdx.x] = sdata[0];
}

__global__ __launch_bounds__(512)
void scan_bsum_kernel(int* __restrict__ bsum, int* __restrict__ rowptr) {
    __shared__ int sdata[512];
    int t = threadIdx.x;
    int v = (t < SCAN_BLOCKS2) ? bsum[t] : 0;
    sdata[t] = v;
    __syncthreads();
    for (int off = 1; off < 512; off <<= 1) {
        int x = (t >= off) ? sdata[t - off] : 0;
        __syncthreads();
        sdata[t] += x;
        __syncthreads();
    }
    if (t < SCAN_BLOCKS2) bsum[t] = sdata[t] - v;
    if (t == 511) rowptr[NTOT2H] = sdata[511];
}

__global__ __launch_bounds__(256)
void scan_apply_kernel(int* __restrict__ rowptr, const int* __restrict__ bsum) {
    __shared__ int sdata[256];
    int t = threadIdx.x;
    int base = blockIdx.x * 1024 + t * 4;
    int4 q = *(const int4*)(rowptr + base);       // read deg before overwrite
    int s = q.x + q.y + q.z + q.w;
    sdata[t] = s;
    __syncthreads();
    for (int off = 1; off < 256; off <<= 1) {
        int x = (t >= off) ? sdata[t - off] : 0;
        __syncthreads();
        sdata[t] += x;
        __syncthreads();
    }
    int run = bsum[blockIdx.x] + sdata[t] - s;
    rowptr[base + 0] = run; run += q.x;
    rowptr[base + 1] = run; run += q.y;
    rowptr[base + 2] = run; run += q.z;
    rowptr[base + 3] = run;
}

// ---------------------------------------------------------------------------
// Deterministic placement (R7 mechanism, quarter-bins): block = (graph,
// chunk, quarter). LDS u16 cursors init from P16 chunk-prefix; pos =
// rowptrH[bin] + prefix + my. colw entry packed u32: col u16 | fp16 w << 16.
// ---------------------------------------------------------------------------
__global__ __launch_bounds__(512)
void placement_kernel(const void* __restrict__ ei, const float* __restrict__ ew,
                      const int* __restrict__ flag,
                      const unsigned short* __restrict__ P16,
                      const int* __restrict__ rowptrH,
                      unsigned* __restrict__ colw) {
    __shared__ unsigned cur[QWORDS];              // 50 KB packed u16 cursors
    const int is64 = *flag;
    int b = blockIdx.x >> 6;
    int k = (blockIdx.x >> 2) & (K_CHUNK - 1);
    int q = blockIdx.x & 3;
    const int binLo = q * QBINS;
    const unsigned* psrc = (const unsigned*)
        (P16 + (long long)(b * K_CHUNK + k) * NB) + q * QWORDS;
    for (int i = threadIdx.x; i < QWORDS; i += 512) cur[i] = psrc[i];
    __syncthreads();
    const long long ebase = (long long)b * 2LL * N_EDGES + (long long)k * CHUNK_E;
    const float* ewb = ew + (long long)b * N_EDGES + (long long)k * CHUNK_E;
    const int* rp = rowptrH + b * NB;
    for (int i = threadIdx.x; i < CHUNK_E; i += 512) {
        int row = load_idx(ei, ebase + i, is64);
        int col = load_idx(ei, ebase + N_EDGES + i, is64);
        int bin = (row << 1) | (col >= CSPLIT);
        unsigned r = (unsigned)(bin - binLo);
        if (r < QBINS) {
            __half hw = __float2half_rn(ewb[i]);
            unsigned short wb = *(unsigned short*)&hw;
            unsigned old = atomicAdd(&cur[r >> 1], 1u << ((r & 1) * 16));
            int my = (int)((old >> ((r & 1) * 16)) & 0xffffu);
            int pos = rp[bin] + my;
            colw[pos] = (unsigned)col | ((unsigned)wb << 16);
        }
    }
}

// ---------------------------------------------------------------------------
// S = act(X) @ W  -> fp16 [N][64]. W in LDS; thread = (row, col-quad).
// ---------------------------------------------------------------------------
template <bool LEAKY>
__global__ __launch_bounds__(256)
void gemm_kernel(const float* __restrict__ X, const float* __restrict__ W,
                 __half* __restrict__ S) {
    __shared__ float Wl[64 * 64];
    int t = threadIdx.x;
    for (int i = t; i < 64 * 64; i += 256) Wl[i] = W[i];
    __syncthreads();

    int dq = t & 15;
    int rl = t >> 4;
    int rowBase = blockIdx.x * 64;
    for (int r = rl; r < 64; r += 16) {
        int row = rowBase + r;
        if (row >= N_NODES) break;
        const float* xr = X + (long long)row * DIM;
        float4 acc = {0.f, 0.f, 0.f, 0.f};
#pragma unroll
        for (int k = 0; k < 64; k += 4) {
            float4 xv = *(const float4*)(xr + k);
            if (LEAKY) {
                xv.x = xv.x > 0.f ? xv.x : NEG_SLOPE * xv.x;
                xv.y = xv.y > 0.f ? xv.y : NEG_SLOPE * xv.y;
                xv.z = xv.z > 0.f ? xv.z : NEG_SLOPE * xv.z;
                xv.w = xv.w > 0.f ? xv.w : NEG_SLOPE * xv.w;
            }
#pragma unroll
            for (int kk = 0; kk < 4; ++kk) {
                float xs = kk == 0 ? xv.x : kk == 1 ? xv.y : kk == 2 ? xv.z : xv.w;
                float4 wv = *(const float4*)(&Wl[(k + kk) * 64 + dq * 4]);
                acc.x += xs * wv.x;
                acc.y += xs * wv.y;
                acc.z += xs * wv.z;
                acc.w += xs * wv.w;
            }
        }
        __half2* o = (__half2*)(S + (long long)row * DIM + dq * 4);
        o[0] = __floats2half2_rn(acc.x, acc.y);
        o[1] = __floats2half2_rn(acc.z, acc.w);
    }
}

// ---------------------------------------------------------------------------
// Pull aggregation, col-half phase h: gathers only from a 3.2 MB support
// slice (fits/replicates in each XCD L2). Wave per node, 2 edge slots x 32
// lanes, __half2 gathers. Phase 0: acc = bias + sumA; phase 1: acc += out.
// ---------------------------------------------------------------------------
__global__ __launch_bounds__(256)
void aggregate_kernel(const int* __restrict__ rowptrH, const unsigned* __restrict__ colw,
                      const __half* __restrict__ src, const float* __restrict__ bias,
                      float* __restrict__ dstBase, int bStart, int h) {
    int bi = blockIdx.x / AGG_BLKS;
    int node = (blockIdx.x % AGG_BLKS) * 4 + (threadIdx.x >> 6);
    int tl = threadIdx.x & 63;
    int lane = tl & 31;                            // dim pair (2l, 2l+1)
    int slot = tl >> 5;                            // even/odd edge slot
    int b = bStart + bi;
    if (node >= N_NODES) return;
    int base = b * NB + node * 2;
    int s = rowptrH[base + h];
    int e = rowptrH[base + h + 1];
    float2 acc = {0.f, 0.f};
    int k = s + slot;
    for (; k + 6 < e; k += 8) {                    // 4 edges/slot = 8/wave
        unsigned c[4];
        float2 v[4];
#pragma unroll
        for (int j = 0; j < 4; ++j) c[j] = colw[k + 2 * j];
#pragma unroll
        for (int j = 0; j < 4; ++j) {
            __half2 hv = *(const __half2*)(src + (long long)(c[j] & 0xffffu) * DIM
                                           + 2 * lane);
            v[j] = __half22float2(hv);
        }
#pragma unroll
        for (int j = 0; j < 4; ++j) {
            unsigned short wb = (unsigned short)(c[j] >> 16);
            float w = __half2float(*(__half*)&wb);
            acc.x += w * v[j].x;
            acc.y += w * v[j].y;
        }
    }
    for (; k < e; k += 2) {
        unsigned c = colw[k];
        __half2 hv = *(const __half2*)(src + (long long)(c & 0xffffu) * DIM + 2 * lane);
        float2 v = __half22float2(hv);
        unsigned short wb = (unsigned short)(c >> 16);
        float w = __half2float(*(__half*)&wb);
        acc.x += w * v.x;
        acc.y += w * v.y;
    }
    acc.x += __shfl_xor(acc.x, 32, 64);
    acc.y += __shfl_xor(acc.y, 32, 64);
    if (slot == 0) {
        float* dp = dstBase + (long long)b * N_NODES * DIM +
                    (long long)node * DIM + 2 * lane;
        float2 o;
        if (h == 0) {
            float2 bb = *(const float2*)(bias + 2 * lane);
            o.x = acc.x + bb.x;
            o.y = acc.y + bb.y;
        } else {
            float2 pv = *(const float2*)dp;
            o.x = acc.x + pv.x;
            o.y = acc.y + pv.y;
        }
        *(float2*)dp = o;
    }
}

extern "C" void kernel_launch(void* const* d_in, const int* in_sizes, int n_in,
                              void* d_out, int out_size, void* d_ws, size_t ws_size,
                              hipStream_t stream) {
    const float* bx = (const float*)d_in[0];
    const void*  ei = d_in[1];
    const float* ew = (const float*)d_in[2];
    const float* W0 = (const float*)d_in[3];
    const float* b0 = (const float*)d_in[4];
    const float* W1 = (const float*)d_in[5];
    const float* b1 = (const float*)d_in[6];
    float* out = (float*)d_out;

    // ---- workspace layout: 33.66 MB total (ws proven >= 40.03 MB, R5-R8) ----
    char* ws = (char*)d_ws;
    int*      flag     = (int*)ws;                       // [0,256)
    int*      bsum     = (int*)(ws + 256);               // 392 ints
    int*      rowptrH  = (int*)(ws + 4096);              // deg->rowptr in place,
                                                         // 401664 ints (1.607 MB)
    unsigned* P32      = (unsigned*)(ws + 1610752);      // 12.845 MB
    unsigned short* P16 = (unsigned short*)P32;
    __half*   support0 = (__half*)(ws + 14455808);       // 6.4 MB
    unsigned* colw     = (unsigned*)(ws + 20855808);     // 12.8 MB (ends 33.66 MB)
    __half*   support1 = (__half*)P32;                   // P16 dead after placement
    const long long ND = (long long)N_NODES * DIM;

    detect_idx_kernel<<<1, 64, 0, stream>>>((const unsigned*)ei, flag);

    // ---- batched atomic-free CSR over (row, colhalf) bins ----
    hist_partial_kernel<<<BATCH * K_CHUNK * 4, 256, 0, stream>>>(ei, flag, P32);
    merge_prefix_kernel<<<NTOT2H / 256, 256, 0, stream>>>(P16, rowptrH);
    scan_partial_kernel<<<SCAN_BLOCKS2, 256, 0, stream>>>(rowptrH, bsum);
    scan_bsum_kernel<<<1, 512, 0, stream>>>(bsum, rowptrH);
    scan_apply_kernel<<<SCAN_BLOCKS2, 256, 0, stream>>>(rowptrH, bsum);

    // ---- layer-1 support (graph-independent, fp16) ----
    gemm_kernel<false><<<(N_NODES + 63) / 64, 256, 0, stream>>>(bx, W0, support0);

    // ---- placement (all graphs, one dispatch) ----
    placement_kernel<<<BATCH * K_CHUNK * 4, 512, 0, stream>>>(
        ei, ew, flag, P16, rowptrH, colw);

    // ---- layer 1: two col-half phases, batched over graphs ----
    aggregate_kernel<<<BATCH * AGG_BLKS, 256, 0, stream>>>(
        rowptrH, colw, support0, b0, out, 0, 0);
    aggregate_kernel<<<BATCH * AGG_BLKS, 256, 0, stream>>>(
        rowptrH, colw, support0, b0, out, 0, 1);

    // ---- layer 2 per graph ----
    for (int b = 0; b < BATCH; ++b) {
        gemm_kernel<true><<<(N_NODES + 63) / 64, 256, 0, stream>>>(
            out + (long long)b * ND, W1, support1);
        aggregate_kernel<<<AGG_BLKS, 256, 0, stream>>>(
            rowptrH, colw, support1, b1, out, b, 0);
        aggregate_kernel<<<AGG_BLKS, 256, 0, stream>>>(
            rowptrH, colw, support1, b1, out, b, 1);
    }
}

// Round 12
// 501.338 us; speedup vs baseline: 1.7820x; 1.2084x over previous
//
#include <hip/hip_runtime.h>
#include <hip/hip_fp16.h>

#define N_NODES 50000
#define NROW    50176                    // padded rows per graph (multiple of 1024)
#define N_EDGES 800000
#define BATCH   4
#define DIM     64
#define NEG_SLOPE 0.2f
#define K_CHUNK 16
#define CHUNK_E (N_EDGES / K_CHUNK)      // 50000 exactly
#define NTOT2   (BATCH * NROW)           // 200704 = 196*1024 exactly
#define SCAN_BLOCKS (NTOT2 / 1024)       // 196
#define HALF_ROWS 25088                  // NROW/2
#define HALF_WORDS 12544                 // HALF_ROWS/2 packed u16 words

// ---------------------------------------------------------------------------
// Index dtype detector (int64 vs int32): if int64 little-endian with values
// < 2^31, every odd 32-bit word is 0. flag=1 for int64, 0 for int32.
// ---------------------------------------------------------------------------
__global__ void detect_idx_kernel(const unsigned* __restrict__ ei, int* flag) {
    __shared__ int any;
    if (threadIdx.x == 0) any = 0;
    __syncthreads();
    unsigned v = ei[threadIdx.x * 2 + 1];
    if (v != 0) atomicOr(&any, 1);
    __syncthreads();
    if (threadIdx.x == 0) *flag = (any ? 0 : 1);
}

__device__ __forceinline__ int load_idx(const void* p, long long i, int is64) {
    if (is64) return (int)(((const long long*)p)[i]);
    return ((const int*)p)[i];
}

// ---------------------------------------------------------------------------
// Histogram stage 1: private LDS histogram per (graph, chunk, row-half).
// u16 counters packed in u32. Coalesced dump, no global atomics.
// ---------------------------------------------------------------------------
__global__ __launch_bounds__(256)
void hist_partial_kernel(const void* __restrict__ ei, const int* __restrict__ flag,
                         unsigned* __restrict__ P32) {
    __shared__ unsigned lds[HALF_WORDS];          // 50 KB
    int t = threadIdx.x;
    int b = blockIdx.x >> 5;
    int k = (blockIdx.x >> 1) & (K_CHUNK - 1);
    int h = blockIdx.x & 1;
    for (int i = t; i < HALF_WORDS; i += 256) lds[i] = 0;
    __syncthreads();
    const int is64 = *flag;
    const int rowLo = h * HALF_ROWS;
    const long long base = (long long)b * 2LL * N_EDGES + (long long)k * CHUNK_E;
    for (int i = t; i < CHUNK_E; i += 256) {
        int row = load_idx(ei, base + i, is64);
        unsigned r = (unsigned)(row - rowLo);
        if (r < HALF_ROWS)
            atomicAdd(&lds[r >> 1], 1u << ((r & 1) * 16));
    }
    __syncthreads();
    unsigned* dst = P32 + (long long)(b * K_CHUNK + k) * (NROW / 2) + h * HALF_WORDS;
    for (int i = t; i < HALF_WORDS; i += 256) dst[i] = lds[i];
}

// ---------------------------------------------------------------------------
// Stage 2: per (b,row): deg = sum_k counts; convert P16 in place to the
// EXCLUSIVE prefix over chunks (u16) -> deterministic placement bases.
// ---------------------------------------------------------------------------
__global__ __launch_bounds__(256)
void merge_prefix_kernel(unsigned short* __restrict__ P16, int* __restrict__ deg4) {
    int gid = blockIdx.x * 256 + threadIdx.x;
    if (gid >= NTOT2) return;
    int b = gid / NROW;
    int row = gid - b * NROW;
    unsigned short* p = P16 + (long long)(b * K_CHUNK) * NROW + row;
    int run = 0;
#pragma unroll
    for (int k = 0; k < K_CHUNK; ++k) {
        int c = p[(long long)k * NROW];
        p[(long long)k * NROW] = (unsigned short)run;
        run += c;
    }
    deg4[gid] = run;
}

// ---------------------------------------------------------------------------
// Hierarchical exclusive scan over deg4[NTOT2] -> rowptr4.
// ---------------------------------------------------------------------------
__global__ __launch_bounds__(256)
void scan_partial_kernel(const int* __restrict__ deg, int* __restrict__ bsum) {
    __shared__ int sdata[256];
    int t = threadIdx.x;
    int base = blockIdx.x * 1024;
    int s = 0;
#pragma unroll
    for (int i = 0; i < 4; ++i) s += deg[base + i * 256 + t];
    sdata[t] = s;
    __syncthreads();
    for (int off = 128; off > 0; off >>= 1) {
        if (t < off) sdata[t] += sdata[t + off];
        __syncthreads();
    }
    if (t == 0) bsum[blockIdx.x] = sdata[0];
}

__global__ __launch_bounds__(256)
void scan_bsum_kernel(int* __restrict__ bsum, int* __restrict__ rowptr) {
    __shared__ int sdata[256];
    int t = threadIdx.x;
    int v = (t < SCAN_BLOCKS) ? bsum[t] : 0;
    sdata[t] = v;
    __syncthreads();
    for (int off = 1; off < 256; off <<= 1) {
        int x = (t >= off) ? sdata[t - off] : 0;
        __syncthreads();
        sdata[t] += x;
        __syncthreads();
    }
    if (t < SCAN_BLOCKS) bsum[t] = sdata[t] - v;
    if (t == 255) rowptr[NTOT2] = sdata[255];
}

__global__ __launch_bounds__(256)
void scan_apply_kernel(const int* __restrict__ deg, const int* __restrict__ bsum,
                       int* __restrict__ rowptr) {
    __shared__ int sdata[256];
    int t = threadIdx.x;
    int base = blockIdx.x * 1024 + t * 4;
    int4 q = *(const int4*)(deg + base);          // NTOT2 exact multiple of 1024
    int s = q.x + q.y + q.z + q.w;
    sdata[t] = s;
    __syncthreads();
    for (int off = 1; off < 256; off <<= 1) {
        int x = (t >= off) ? sdata[t - off] : 0;
        __syncthreads();
        sdata[t] += x;
        __syncthreads();
    }
    int run = bsum[blockIdx.x] + sdata[t] - s;
    rowptr[base + 0] = run; run += q.x;
    rowptr[base + 1] = run; run += q.y;
    rowptr[base + 2] = run; run += q.z;
    rowptr[base + 3] = run;
}

// ---------------------------------------------------------------------------
// Deterministic placement (R7 proven form + packed 4 B entries): NO global
// atomics. Class-clustered block mapping. LDS u16 cursors (packed u32) start
// at P16 chunk-prefix; pos = rowptr[row] + prefix + my.
// colw entry u32 = col(u16) | fp16 weight << 16   (payload 12.8 MB, was 25.6)
// ---------------------------------------------------------------------------
__global__ __launch_bounds__(512)
void placement_kernel(const void* __restrict__ ei, const float* __restrict__ ew,
                      const int* __restrict__ flag,
                      const unsigned short* __restrict__ P16,
                      const int* __restrict__ rowptr4,
                      unsigned* __restrict__ colw, int bStart, int sub) {
    __shared__ unsigned lds[HALF_WORDS];          // 50 KB packed u16 cursors
    const int is64 = *flag;
    const int nc = gridDim.x >> 4;                // classes = nGraphs*2
    int c = blockIdx.x % nc;
    int k = blockIdx.x / nc;                      // chunk 0..15
    int b = bStart + (c >> 1);
    int h = c & 1;
    const int rowLo = h * HALF_ROWS;
    const unsigned* psrc =
        (const unsigned*)(P16 + (long long)(b * K_CHUNK + k) * NROW + rowLo);
    for (int i = threadIdx.x; i < HALF_WORDS; i += 512) lds[i] = psrc[i];
    __syncthreads();
    const long long ebase = (long long)b * 2LL * N_EDGES + (long long)k * CHUNK_E;
    const float* ewb = ew + (long long)b * N_EDGES + (long long)k * CHUNK_E;
    const int* rp = rowptr4 + b * NROW;
    for (int i = threadIdx.x; i < CHUNK_E; i += 512) {
        int row = load_idx(ei, ebase + i, is64);
        unsigned r = (unsigned)(row - rowLo);
        if (r < HALF_ROWS) {
            int col = load_idx(ei, ebase + N_EDGES + i, is64);
            __half hw = __float2half_rn(ewb[i]);
            unsigned short wb = *(unsigned short*)&hw;
            unsigned old = atomicAdd(&lds[r >> 1], 1u << ((r & 1) * 16));
            int my = (int)((old >> ((r & 1) * 16)) & 0xffffu);
            int pos = rp[row] + my - sub;
            colw[pos] = (unsigned)col | ((unsigned)wb << 16);
        }
    }
}

// ---------------------------------------------------------------------------
// S = act(X) @ W  -> fp16 [N][64]. W in LDS; thread = (row, col-quad).
// ---------------------------------------------------------------------------
template <bool LEAKY>
__global__ __launch_bounds__(256)
void gemm_kernel(const float* __restrict__ X, const float* __restrict__ W,
                 __half* __restrict__ S) {
    __shared__ float Wl[64 * 64];
    int t = threadIdx.x;
    for (int i = t; i < 64 * 64; i += 256) Wl[i] = W[i];
    __syncthreads();

    int dq = t & 15;
    int rl = t >> 4;
    int rowBase = blockIdx.x * 64;
    for (int r = rl; r < 64; r += 16) {
        int row = rowBase + r;
        if (row >= N_NODES) break;
        const float* xr = X + (long long)row * DIM;
        float4 acc = {0.f, 0.f, 0.f, 0.f};
#pragma unroll
        for (int k = 0; k < 64; k += 4) {
            float4 xv = *(const float4*)(xr + k);
            if (LEAKY) {
                xv.x = xv.x > 0.f ? xv.x : NEG_SLOPE * xv.x;
                xv.y = xv.y > 0.f ? xv.y : NEG_SLOPE * xv.y;
                xv.z = xv.z > 0.f ? xv.z : NEG_SLOPE * xv.z;
                xv.w = xv.w > 0.f ? xv.w : NEG_SLOPE * xv.w;
            }
#pragma unroll
            for (int kk = 0; kk < 4; ++kk) {
                float xs = kk == 0 ? xv.x : kk == 1 ? xv.y : kk == 2 ? xv.z : xv.w;
                float4 wv = *(const float4*)(&Wl[(k + kk) * 64 + dq * 4]);
                acc.x += xs * wv.x;
                acc.y += xs * wv.y;
                acc.z += xs * wv.z;
                acc.w += xs * wv.w;
            }
        }
        __half2* o = (__half2*)(S + (long long)row * DIM + dq * 4);
        o[0] = __floats2half2_rn(acc.x, acc.y);
        o[1] = __floats2half2_rn(acc.z, acc.w);
    }
}

// ---------------------------------------------------------------------------
// Pull aggregation (R7 proven form, packed colw): wave per node, two edge
// slots x 32 lanes, __half2 gathers; shfl_xor(32) combine; float2 store.
// ---------------------------------------------------------------------------
__global__ __launch_bounds__(256)
void aggregate_kernel(const int* __restrict__ rowptr4, const unsigned* __restrict__ colw,
                      const __half* __restrict__ src, const float* __restrict__ bias,
                      float* __restrict__ dstBase, int bStart, int colwLocal) {
    const int BLKS = NROW / 4;                     // 12544
    int bi = blockIdx.x / BLKS;
    int node = (blockIdx.x % BLKS) * 4 + (threadIdx.x >> 6);
    int tl = threadIdx.x & 63;
    int lane = tl & 31;                            // dim pair id (dims 2l, 2l+1)
    int slot = tl >> 5;                            // 0: even edges, 1: odd edges
    int b = bStart + bi;
    if (node >= N_NODES) return;
    const int* rp = rowptr4 + b * NROW;
    int sub = colwLocal ? b * N_EDGES : 0;
    int s = rp[node] - sub;
    int e = rp[node + 1] - sub;
    float2 acc = {0.f, 0.f};
    int k = s + slot;
    for (; k + 14 < e; k += 16) {                  // 8 pair-steps = 16 edges/wave
        unsigned c[8];
        float2 v[8];
#pragma unroll
        for (int j = 0; j < 8; ++j) c[j] = colw[k + 2 * j];
#pragma unroll
        for (int j = 0; j < 8; ++j) {
            __half2 h = *(const __half2*)(src + (long long)(c[j] & 0xffffu) * DIM
                                          + 2 * lane);
            v[j] = __half22float2(h);
        }
#pragma unroll
        for (int j = 0; j < 8; ++j) {
            unsigned short wb = (unsigned short)(c[j] >> 16);
            float w = __half2float(*(__half*)&wb);
            acc.x += w * v[j].x;
            acc.y += w * v[j].y;
        }
    }
    for (; k < e; k += 2) {
        unsigned c = colw[k];
        __half2 h = *(const __half2*)(src + (long long)(c & 0xffffu) * DIM + 2 * lane);
        float2 v = __half22float2(h);
        unsigned short wb = (unsigned short)(c >> 16);
        float w = __half2float(*(__half*)&wb);
        acc.x += w * v.x;
        acc.y += w * v.y;
    }
    acc.x += __shfl_xor(acc.x, 32, 64);
    acc.y += __shfl_xor(acc.y, 32, 64);
    if (slot == 0) {
        float2 bb = *(const float2*)(bias + 2 * lane);
        float2 o;
        o.x = acc.x + bb.x;
        o.y = acc.y + bb.y;
        *(float2*)(dstBase + (long long)b * N_NODES * DIM +
                   (long long)node * DIM + 2 * lane) = o;
    }
}

extern "C" void kernel_launch(void* const* d_in, const int* in_sizes, int n_in,
                              void* d_out, int out_size, void* d_ws, size_t ws_size,
                              hipStream_t stream) {
    const float* bx = (const float*)d_in[0];
    const void*  ei = d_in[1];
    const float* ew = (const float*)d_in[2];
    const float* W0 = (const float*)d_in[3];
    const float* b0 = (const float*)d_in[4];
    const float* W1 = (const float*)d_in[5];
    const float* b1 = (const float*)d_in[6];
    float* out = (float*)d_out;

    // ---- workspace layout (big path = 27.23 MB; ws proven >= 40 MB) ----
    char* ws = (char*)d_ws;
    int*      flag     = (int*)ws;                       // [0,256)
    int*      bsum     = (int*)(ws + 256);               // [256,1280)
    int*      deg4     = (int*)(ws + 1280);              // [1280,804096)
    int*      rowptr4  = (int*)(ws + 804096);            // [804096,1607168)
    unsigned* P32      = (unsigned*)(ws + 1607168);      // [1607168,8029696) 6.42MB
    unsigned short* P16 = (unsigned short*)P32;
    __half*   support0 = (__half*)(ws + 8029696);        // 6.4 MB
    unsigned* colw     = (unsigned*)(ws + 14429696);     // big: 12.8 MB (packed)
    const size_t NEED_BIG = 14429696ull + (size_t)BATCH * N_EDGES * 4ull; // 27.23MB
    const bool big = ws_size >= NEED_BIG;
    __half* support1 = big ? (__half*)P32                // P16 dead after placement
                           : (__half*)(ws + 14429696 + (size_t)N_EDGES * 4);
    const long long ND = (long long)N_NODES * DIM;

    detect_idx_kernel<<<1, 64, 0, stream>>>((const unsigned*)ei, flag);

    // ---- batched atomic-free CSR skeleton (row bins, R7 form) ----
    hist_partial_kernel<<<BATCH * K_CHUNK * 2, 256, 0, stream>>>(ei, flag, P32);
    merge_prefix_kernel<<<(NTOT2 + 255) / 256, 256, 0, stream>>>(P16, deg4);
    scan_partial_kernel<<<SCAN_BLOCKS, 256, 0, stream>>>(deg4, bsum);
    scan_bsum_kernel<<<1, 256, 0, stream>>>(bsum, rowptr4);
    scan_apply_kernel<<<SCAN_BLOCKS, 256, 0, stream>>>(deg4, bsum, rowptr4);

    // ---- layer-1 support (graph-independent, fp16) ----
    gemm_kernel<false><<<(N_NODES + 63) / 64, 256, 0, stream>>>(bx, W0, support0);

    const int AGG_BLKS = NROW / 4;                 // 12544 per graph

    if (big) {
        placement_kernel<<<BATCH * K_CHUNK * 2, 512, 0, stream>>>(
            ei, ew, flag, P16, rowptr4, colw, 0, 0);
        aggregate_kernel<<<BATCH * AGG_BLKS, 256, 0, stream>>>(
            rowptr4, colw, support0, b0, out, 0, 0);
        for (int b = 0; b < BATCH; ++b) {
            gemm_kernel<true><<<(N_NODES + 63) / 64, 256, 0, stream>>>(
                out + (long long)b * ND, W1, support1);   // P16 dead after placement
            aggregate_kernel<<<AGG_BLKS, 256, 0, stream>>>(
                rowptr4, colw, support1, b1, out, b, 0);
        }
    } else {
        for (int b = 0; b < BATCH; ++b) {
            placement_kernel<<<K_CHUNK * 2, 512, 0, stream>>>(
                ei, ew, flag, P16, rowptr4, colw, b, b * N_EDGES);
            aggregate_kernel<<<AGG_BLKS, 256, 0, stream>>>(
                rowptr4, colw, support0, b0, out, b, 1);
            gemm_kernel<true><<<(N_NODES + 63) / 64, 256, 0, stream>>>(
                out + (long long)b * ND, W1, support1);
            aggregate_kernel<<<AGG_BLKS, 256, 0, stream>>>(
                rowptr4, colw, support1, b1, out, b, 1);
        }
    }
}